// Round 1
// baseline (479.364 us; speedup 1.0000x reference)
//
#include <hip/hip_runtime.h>

namespace {

typedef _Float16 half_t;
typedef _Float16 half2_t __attribute__((ext_vector_type(2)));
typedef _Float16 half4_t __attribute__((ext_vector_type(4)));

constexpr int Wd = 160, Hd = 192, Dd = 160;
constexpr int TX = 16, TY = 16, CZ = 40;
constexpr int HW = Hd * Wd;
constexpr int LIVE = CZ + 8;               // 48 slices per block
constexpr float INV_K = 1.0f / 729.0f;
constexpr float INV_TOT = 1.0f / 9830400.0f;   // 2*160*192*160
constexpr int R4 = 17;     // xs4h row stride in half4 units (16 cols + 1 pad)
constexpr int RTH = 68;    // xsTh row stride in half units (x at 4*x)
constexpr int ROWS = 26;   // 24 halo rows + 2 pad rows absorbing lanes 240..255

// ROUND 11: z-ring LDS -> registers. R10 counters: VALUBusy 47%, HBM 28%,
// occupancy 23.5% ~= 2 blocks/CU -- latency-bound, no pipe saturated. The
// 23 KB ring is thread-private with STATIC slot index (u%9 after unroll),
// so it moves to ~27 VGPRs (84 -> ~111). LDS 37.4 KB -> 14.3 KB; with
// __launch_bounds__(256,4) the VGPR budget (128) gives 4 waves/SIMD ->
// 4 blocks/CU: twice the independent barrier groups to fill stalls, and
// -4 LDS instrs (-~15% LDS pipe) per wave-slice. Slot/parity tokens are
// literal (manual 18-step expansion) so ring indices stay compile-time.

__global__ __launch_bounds__(256, 4)
void ncc_main(const float* __restrict__ inp, const float* __restrict__ tgt,
              float* __restrict__ out)
{
    __shared__ half4_t xs4h[2][ROWS * R4];   // 2 x 3536 B
    __shared__ half_t  xsTh[2][ROWS * RTH];  // 2 x 3536 B
    __shared__ float   red[4];

    const int tid = threadIdx.x;
    const int n  = (int)blockIdx.z >> 2;
    const int zc = (int)blockIdx.z & 3;
    const int x0 = blockIdx.x * TX, y0 = blockIdx.y * TY, z0 = zc * CZ;

    // ---- phase-1 decode: (row r 0..25) x (half h) x (field f)
    const int f = tid % 5;
    const int j = tid / 5;
    const int r = j >> 1, h = j & 1;
    const int gy = y0 - 4 + r;
    const bool yok = (tid < 240) && (gy >= 0) && (gy < Hd);
    const int gyc = min(max(gy, 0), Hd - 1);
    const int gxb = x0 - 4 + 8 * h;
    const bool uI = (f == 0) || (f == 1) || (f == 3);
    const float bI = (f == 0) ? 1.f : 0.f;
    const float bT = (f == 1 || f == 2) ? 0.5f : 0.f;
    const float bC = (f == 1 || f == 2) ? 0.5f : ((f >= 3) ? 1.f : 0.f);

#define DECODE(c) \
    int voff##c; float aI##c, aTC##c; \
    { const int gx = gxb + 4 * c; \
      const float m = (yok && gx >= 0 && gx < Wd) ? 1.f : 0.f; \
      const int gxc = min(max(gx, 0), Wd - 4); \
      voff##c = gyc * Wd + gxc; \
      aI##c = uI ? m : 0.f; aTC##c = uI ? 0.f : 0.5f * m; }
    DECODE(0) DECODE(1) DECODE(2) DECODE(3)
#undef DECODE

    const int nb = n * (Dd * HW);            // < 2^24, int math is exact
    const float* baseI = inp + nb;           // uniform -> SGPR pair
    const float* baseT = tgt + nb;

    // unified store base (both layouts are stride-4 halves): static imm offsets
    const int stoff = (f < 4) ? ((r * R4) * 4 + 32 * h + f) : (r * RTH + 32 * h);
    half_t* const st0 = (f < 4) ? ((half_t*)xs4h[0] + stoff) : (xsTh[0] + stoff);
    half_t* const st1 = (f < 4) ? ((half_t*)xs4h[1] + stoff) : (xsTh[1] + stoff);

    // ---- phase-2 decode: one output column (yi, xi)
    const int yi = tid >> 4, xi = tid & 15;
    const half4_t* const rd4_0 = &xs4h[0][yi * R4 + xi];
    const half4_t* const rd4_1 = &xs4h[1][yi * R4 + xi];
    const half_t*  const rdT_0 = &xsTh[0][yi * RTH + 4 * xi];
    const half_t*  const rdT_1 = &xsTh[1][yi * RTH + 4 * xi];

    float4 S4 = make_float4(0.f, 0.f, 0.f, 0.f);
    float ST = 0.f, acc = 0.f;

    // z-ring in registers: slot index is a literal token in every access
    half2_t rg01[9], rg23[9];
    half_t  rgT[9];
    #pragma unroll
    for (int q = 0; q < 9; ++q) {
        rg01[q] = (half2_t)0; rg23[q] = (half2_t)0; rgT[q] = (half_t)0.f;
    }

    // two prefetch sets, roles alternate with static slice parity
#define DECL_SET(S) \
    float4 S##I0, S##I1, S##I2, S##I3, S##T0, S##T1, S##T2, S##T3; \
    S##I0 = S##I1 = S##I2 = S##I3 = make_float4(0.f, 0.f, 0.f, 0.f); \
    S##T0 = S##T1 = S##T2 = S##T3 = S##I0;
    DECL_SET(A) DECL_SET(B)
#undef DECL_SET

#define PRELOAD(S, zz) { \
    const float* pI = baseI + (zz) * HW; \
    const float* pT = baseT + (zz) * HW; \
    S##I0 = *(const float4*)(pI + voff0); S##T0 = *(const float4*)(pT + voff0); \
    S##I1 = *(const float4*)(pI + voff1); S##T1 = *(const float4*)(pT + voff1); \
    S##I2 = *(const float4*)(pI + voff2); S##T2 = *(const float4*)(pT + voff2); \
    S##I3 = *(const float4*)(pI + voff3); S##T3 = *(const float4*)(pT + voff3); }

    // prologue: s=0 -> set A (even), s=1 -> set B (odd)
    if (z0 - 4 >= 0) PRELOAD(A, z0 - 4)
    if (z0 - 3 >= 0) PRELOAD(B, z0 - 3)

#define PRODC(S, c, P0, P1, P2, P3) { \
    P0 = fmaf(S##I##c.x, aI##c, fmaf(S##T##c.x, aTC##c, aTC##c)) * fmaf(S##I##c.x, bI, fmaf(S##T##c.x, bT, bC)); \
    P1 = fmaf(S##I##c.y, aI##c, fmaf(S##T##c.y, aTC##c, aTC##c)) * fmaf(S##I##c.y, bI, fmaf(S##T##c.y, bT, bC)); \
    P2 = fmaf(S##I##c.z, aI##c, fmaf(S##T##c.z, aTC##c, aTC##c)) * fmaf(S##I##c.z, bI, fmaf(S##T##c.z, bT, bC)); \
    P3 = fmaf(S##I##c.w, aI##c, fmaf(S##T##c.w, aTC##c, aTC##c)) * fmaf(S##I##c.w, bI, fmaf(S##T##c.w, bT, bC)); }

    // body for one slice; SET = prefetch set holding slice s (also target of
    // the s+2 load, same parity); U = literal step 0..17; SL = literal U%9
#define SLICE_BODY(SET, U, SL) { \
    const int s = tb + (U); \
    const int zi = z0 - 4 + s; \
    const bool zok = (zi >= 0) && (zi < Dd);        /* uniform */ \
    float o0, o1, o2, o3, o4, o5, o6, o7; \
    if (zok) { \
        float p0, p1, p2, p3, p4, p5, p6, p7; \
        float p8, p9, p10, p11, p12, p13, p14, p15; \
        PRODC(SET, 0, p0,  p1,  p2,  p3) \
        PRODC(SET, 1, p4,  p5,  p6,  p7) \
        PRODC(SET, 2, p8,  p9,  p10, p11) \
        PRODC(SET, 3, p12, p13, p14, p15) \
        float ss = p0 + p1 + p2 + p3 + p4 + p5 + p6 + p7 + p8; \
        o0 = ss; \
        ss += p9  - p0; o1 = ss; \
        ss += p10 - p1; o2 = ss; \
        ss += p11 - p2; o3 = ss; \
        ss += p12 - p3; o4 = ss; \
        ss += p13 - p4; o5 = ss; \
        ss += p14 - p5; o6 = ss; \
        ss += p15 - p6; o7 = ss; \
    } \
    {   /* prefetch slice s+2 into the same set (depth-2 pipeline) */ \
        const int zi2 = z0 - 2 + s; \
        if ((s + 2) < LIVE && zi2 >= 0 && zi2 < Dd) PRELOAD(SET, zi2) \
    } \
    if (zok) { \
        half_t* const st = ((U) & 1) ? st1 : st0; \
        st[0]  = (half_t)o0; st[4]  = (half_t)o1; \
        st[8]  = (half_t)o2; st[12] = (half_t)o3; \
        st[16] = (half_t)o4; st[20] = (half_t)o5; \
        st[24] = (half_t)o6; st[28] = (half_t)o7; \
    } \
    __syncthreads();                                /* single barrier */ \
    half2_t a01 = (half2_t)0, a23 = (half2_t)0; \
    half_t aT = (half_t)0.f; \
    if (zok) { \
        const half4_t* const rd4 = ((U) & 1) ? rd4_1 : rd4_0; \
        const half_t*  const rdT = ((U) & 1) ? rdT_1 : rdT_0; \
        _Pragma("unroll") \
        for (int k = 0; k < 9; ++k) { \
            const half4_t v = rd4[k * R4]; \
            const half2_t vlo = {v.x, v.y}; \
            const half2_t vhi = {v.z, v.w}; \
            a01 += vlo; a23 += vhi; \
            aT += rdT[k * RTH]; \
        } \
    } \
    {   /* register z-ring (static literal slot, thread-private) */ \
        const half2_t o01 = rg01[SL]; \
        const half2_t o23 = rg23[SL]; \
        const half_t  oT  = rgT[SL]; \
        S4.x += (float)a01.x - (float)o01.x; \
        S4.y += (float)a01.y - (float)o01.y; \
        S4.z += (float)a23.x - (float)o23.x; \
        S4.w += (float)a23.y - (float)o23.y; \
        ST   += (float)aT - (float)oT; \
        rg01[SL] = a01; rg23[SL] = a23; rgT[SL] = aT; \
    } \
    if (s >= 8) {                                   /* output z = z0+s-8 */ \
        const float sii = S4.x, sit = S4.y, stt = S4.z, si = S4.w, stv = ST; \
        const float cross = sit - si * stv * INV_K; \
        const float tvar  = stt - stv * stv * INV_K; \
        const float ivar  = sii - si  * si  * INV_K; \
        acc += cross * cross * __builtin_amdgcn_rcpf(tvar * ivar + 1e-5f); \
    } }

#define STEP(U, SL, SET) if (tb + (U) < LIVE) SLICE_BODY(SET, U, SL)

    for (int tb = 0; tb < 54; tb += 18) {          // 48 live; 18-step expansion
        STEP(0, 0, A)  STEP(1, 1, B)  STEP(2, 2, A)  STEP(3, 3, B)
        STEP(4, 4, A)  STEP(5, 5, B)  STEP(6, 6, A)  STEP(7, 7, B)
        STEP(8, 8, A)  STEP(9, 0, B)  STEP(10, 1, A) STEP(11, 2, B)
        STEP(12, 3, A) STEP(13, 4, B) STEP(14, 5, A) STEP(15, 6, B)
        STEP(16, 7, A) STEP(17, 8, B)
    }
#undef STEP
#undef SLICE_BODY
#undef PRELOAD
#undef PRODC

    // ---- block reduction + fused finalize (one atomic per block)
    #pragma unroll
    for (int off = 32; off > 0; off >>= 1) acc += __shfl_down(acc, off, 64);
    if ((tid & 63) == 0) red[tid >> 6] = acc;
    __syncthreads();
    if (tid == 0) {
        const float tot = red[0] + red[1] + red[2] + red[3];
        atomicAdd(out, -tot * INV_TOT);
    }
}

} // namespace

extern "C" void kernel_launch(void* const* d_in, const int* in_sizes, int n_in,
                              void* d_out, int out_size, void* d_ws, size_t ws_size,
                              hipStream_t stream)
{
    const float* inp = (const float*)d_in[0];
    const float* tgt = (const float*)d_in[1];
    float* out = (float*)d_out;

    hipMemsetAsync(d_out, 0, sizeof(float), stream);   // d_out re-poisoned each call
    dim3 grid(Wd / TX, Hd / TY, 2 * (Dd / CZ));        // (10,12,8) = 960 blocks
    ncc_main<<<grid, 256, 0, stream>>>(inp, tgt, out);
}

// Round 2
// 385.318 us; speedup vs baseline: 1.2441x; 1.2441x over previous
//
#include <hip/hip_runtime.h>

namespace {

typedef _Float16 half_t;
typedef _Float16 half2_t __attribute__((ext_vector_type(2)));
typedef _Float16 half4_t __attribute__((ext_vector_type(4)));

constexpr int Wd = 160, Hd = 192, Dd = 160;
constexpr int TX = 16, TY = 16, CZ = 40;
constexpr int HW = Hd * Wd;
constexpr int LIVE = CZ + 8;               // 48 slices per block
constexpr float INV_K = 1.0f / 729.0f;
constexpr float INV_TOT = 1.0f / 9830400.0f;   // 2*160*192*160
constexpr int R4 = 17;     // xs4h row stride in half4 units (16 cols + 1 pad)
constexpr int RTH = 68;    // xsTh row stride in half units (x at 4*x)
constexpr int ROWS = 26;   // 24 halo rows + 2 pad rows absorbing lanes 240..255

// ROUND 12: register ring, RELAXED bounds. R11's __launch_bounds__(256,4)
// cut the VGPR budget to 128 < ~150 true demand (A/B float4 pipeline sets
// = 64 regs alone) -> allocator spilled pipeline state to scratch every
// slice: WRITE_SIZE 30 KB -> 577 MB, VALUBusy 11%, 2.8x regression.
// (256,3) gives budget ~168 >= demand -> no spills, 3 waves/SIMD =
// 3 blocks/CU (vs R10's 2). LDS stays 14.3 KB (ring is in registers with
// literal slot indices via the manual 18-step expansion).

__global__ __launch_bounds__(256, 3)
void ncc_main(const float* __restrict__ inp, const float* __restrict__ tgt,
              float* __restrict__ out)
{
    __shared__ half4_t xs4h[2][ROWS * R4];   // 2 x 3536 B
    __shared__ half_t  xsTh[2][ROWS * RTH];  // 2 x 3536 B
    __shared__ float   red[4];

    const int tid = threadIdx.x;
    const int n  = (int)blockIdx.z >> 2;
    const int zc = (int)blockIdx.z & 3;
    const int x0 = blockIdx.x * TX, y0 = blockIdx.y * TY, z0 = zc * CZ;

    // ---- phase-1 decode: (row r 0..25) x (half h) x (field f)
    const int f = tid % 5;
    const int j = tid / 5;
    const int r = j >> 1, h = j & 1;
    const int gy = y0 - 4 + r;
    const bool yok = (tid < 240) && (gy >= 0) && (gy < Hd);
    const int gyc = min(max(gy, 0), Hd - 1);
    const int gxb = x0 - 4 + 8 * h;
    const bool uI = (f == 0) || (f == 1) || (f == 3);
    const float bI = (f == 0) ? 1.f : 0.f;
    const float bT = (f == 1 || f == 2) ? 0.5f : 0.f;
    const float bC = (f == 1 || f == 2) ? 0.5f : ((f >= 3) ? 1.f : 0.f);

#define DECODE(c) \
    int voff##c; float aI##c, aTC##c; \
    { const int gx = gxb + 4 * c; \
      const float m = (yok && gx >= 0 && gx < Wd) ? 1.f : 0.f; \
      const int gxc = min(max(gx, 0), Wd - 4); \
      voff##c = gyc * Wd + gxc; \
      aI##c = uI ? m : 0.f; aTC##c = uI ? 0.f : 0.5f * m; }
    DECODE(0) DECODE(1) DECODE(2) DECODE(3)
#undef DECODE

    const int nb = n * (Dd * HW);            // < 2^24, int math is exact
    const float* baseI = inp + nb;           // uniform -> SGPR pair
    const float* baseT = tgt + nb;

    // unified store base (both layouts are stride-4 halves): static imm offsets
    const int stoff = (f < 4) ? ((r * R4) * 4 + 32 * h + f) : (r * RTH + 32 * h);
    half_t* const st0 = (f < 4) ? ((half_t*)xs4h[0] + stoff) : (xsTh[0] + stoff);
    half_t* const st1 = (f < 4) ? ((half_t*)xs4h[1] + stoff) : (xsTh[1] + stoff);

    // ---- phase-2 decode: one output column (yi, xi)
    const int yi = tid >> 4, xi = tid & 15;
    const half4_t* const rd4_0 = &xs4h[0][yi * R4 + xi];
    const half4_t* const rd4_1 = &xs4h[1][yi * R4 + xi];
    const half_t*  const rdT_0 = &xsTh[0][yi * RTH + 4 * xi];
    const half_t*  const rdT_1 = &xsTh[1][yi * RTH + 4 * xi];

    float4 S4 = make_float4(0.f, 0.f, 0.f, 0.f);
    float ST = 0.f, acc = 0.f;

    // z-ring in registers: slot index is a literal token in every access
    half2_t rg01[9], rg23[9];
    half_t  rgT[9];
    #pragma unroll
    for (int q = 0; q < 9; ++q) {
        rg01[q] = (half2_t)0; rg23[q] = (half2_t)0; rgT[q] = (half_t)0.f;
    }

    // two prefetch sets, roles alternate with static slice parity
#define DECL_SET(S) \
    float4 S##I0, S##I1, S##I2, S##I3, S##T0, S##T1, S##T2, S##T3; \
    S##I0 = S##I1 = S##I2 = S##I3 = make_float4(0.f, 0.f, 0.f, 0.f); \
    S##T0 = S##T1 = S##T2 = S##T3 = S##I0;
    DECL_SET(A) DECL_SET(B)
#undef DECL_SET

#define PRELOAD(S, zz) { \
    const float* pI = baseI + (zz) * HW; \
    const float* pT = baseT + (zz) * HW; \
    S##I0 = *(const float4*)(pI + voff0); S##T0 = *(const float4*)(pT + voff0); \
    S##I1 = *(const float4*)(pI + voff1); S##T1 = *(const float4*)(pT + voff1); \
    S##I2 = *(const float4*)(pI + voff2); S##T2 = *(const float4*)(pT + voff2); \
    S##I3 = *(const float4*)(pI + voff3); S##T3 = *(const float4*)(pT + voff3); }

    // prologue: s=0 -> set A (even), s=1 -> set B (odd)
    if (z0 - 4 >= 0) PRELOAD(A, z0 - 4)
    if (z0 - 3 >= 0) PRELOAD(B, z0 - 3)

#define PRODC(S, c, P0, P1, P2, P3) { \
    P0 = fmaf(S##I##c.x, aI##c, fmaf(S##T##c.x, aTC##c, aTC##c)) * fmaf(S##I##c.x, bI, fmaf(S##T##c.x, bT, bC)); \
    P1 = fmaf(S##I##c.y, aI##c, fmaf(S##T##c.y, aTC##c, aTC##c)) * fmaf(S##I##c.y, bI, fmaf(S##T##c.y, bT, bC)); \
    P2 = fmaf(S##I##c.z, aI##c, fmaf(S##T##c.z, aTC##c, aTC##c)) * fmaf(S##I##c.z, bI, fmaf(S##T##c.z, bT, bC)); \
    P3 = fmaf(S##I##c.w, aI##c, fmaf(S##T##c.w, aTC##c, aTC##c)) * fmaf(S##I##c.w, bI, fmaf(S##T##c.w, bT, bC)); }

    // body for one slice; SET = prefetch set holding slice s (also target of
    // the s+2 load, same parity); U = literal step 0..17; SL = literal U%9
#define SLICE_BODY(SET, U, SL) { \
    const int s = tb + (U); \
    const int zi = z0 - 4 + s; \
    const bool zok = (zi >= 0) && (zi < Dd);        /* uniform */ \
    float o0, o1, o2, o3, o4, o5, o6, o7; \
    if (zok) { \
        float p0, p1, p2, p3, p4, p5, p6, p7; \
        float p8, p9, p10, p11, p12, p13, p14, p15; \
        PRODC(SET, 0, p0,  p1,  p2,  p3) \
        PRODC(SET, 1, p4,  p5,  p6,  p7) \
        PRODC(SET, 2, p8,  p9,  p10, p11) \
        PRODC(SET, 3, p12, p13, p14, p15) \
        float ss = p0 + p1 + p2 + p3 + p4 + p5 + p6 + p7 + p8; \
        o0 = ss; \
        ss += p9  - p0; o1 = ss; \
        ss += p10 - p1; o2 = ss; \
        ss += p11 - p2; o3 = ss; \
        ss += p12 - p3; o4 = ss; \
        ss += p13 - p4; o5 = ss; \
        ss += p14 - p5; o6 = ss; \
        ss += p15 - p6; o7 = ss; \
    } \
    {   /* prefetch slice s+2 into the same set (depth-2 pipeline) */ \
        const int zi2 = z0 - 2 + s; \
        if ((s + 2) < LIVE && zi2 >= 0 && zi2 < Dd) PRELOAD(SET, zi2) \
    } \
    if (zok) { \
        half_t* const st = ((U) & 1) ? st1 : st0; \
        st[0]  = (half_t)o0; st[4]  = (half_t)o1; \
        st[8]  = (half_t)o2; st[12] = (half_t)o3; \
        st[16] = (half_t)o4; st[20] = (half_t)o5; \
        st[24] = (half_t)o6; st[28] = (half_t)o7; \
    } \
    __syncthreads();                                /* single barrier */ \
    half2_t a01 = (half2_t)0, a23 = (half2_t)0; \
    half_t aT = (half_t)0.f; \
    if (zok) { \
        const half4_t* const rd4 = ((U) & 1) ? rd4_1 : rd4_0; \
        const half_t*  const rdT = ((U) & 1) ? rdT_1 : rdT_0; \
        _Pragma("unroll") \
        for (int k = 0; k < 9; ++k) { \
            const half4_t v = rd4[k * R4]; \
            const half2_t vlo = {v.x, v.y}; \
            const half2_t vhi = {v.z, v.w}; \
            a01 += vlo; a23 += vhi; \
            aT += rdT[k * RTH]; \
        } \
    } \
    {   /* register z-ring (static literal slot, thread-private) */ \
        const half2_t o01 = rg01[SL]; \
        const half2_t o23 = rg23[SL]; \
        const half_t  oT  = rgT[SL]; \
        S4.x += (float)a01.x - (float)o01.x; \
        S4.y += (float)a01.y - (float)o01.y; \
        S4.z += (float)a23.x - (float)o23.x; \
        S4.w += (float)a23.y - (float)o23.y; \
        ST   += (float)aT - (float)oT; \
        rg01[SL] = a01; rg23[SL] = a23; rgT[SL] = aT; \
    } \
    if (s >= 8) {                                   /* output z = z0+s-8 */ \
        const float sii = S4.x, sit = S4.y, stt = S4.z, si = S4.w, stv = ST; \
        const float cross = sit - si * stv * INV_K; \
        const float tvar  = stt - stv * stv * INV_K; \
        const float ivar  = sii - si  * si  * INV_K; \
        acc += cross * cross * __builtin_amdgcn_rcpf(tvar * ivar + 1e-5f); \
    } }

#define STEP(U, SL, SET) if (tb + (U) < LIVE) SLICE_BODY(SET, U, SL)

    for (int tb = 0; tb < 54; tb += 18) {          // 48 live; 18-step expansion
        STEP(0, 0, A)  STEP(1, 1, B)  STEP(2, 2, A)  STEP(3, 3, B)
        STEP(4, 4, A)  STEP(5, 5, B)  STEP(6, 6, A)  STEP(7, 7, B)
        STEP(8, 8, A)  STEP(9, 0, B)  STEP(10, 1, A) STEP(11, 2, B)
        STEP(12, 3, A) STEP(13, 4, B) STEP(14, 5, A) STEP(15, 6, B)
        STEP(16, 7, A) STEP(17, 8, B)
    }
#undef STEP
#undef SLICE_BODY
#undef PRELOAD
#undef PRODC

    // ---- block reduction + fused finalize (one atomic per block)
    #pragma unroll
    for (int off = 32; off > 0; off >>= 1) acc += __shfl_down(acc, off, 64);
    if ((tid & 63) == 0) red[tid >> 6] = acc;
    __syncthreads();
    if (tid == 0) {
        const float tot = red[0] + red[1] + red[2] + red[3];
        atomicAdd(out, -tot * INV_TOT);
    }
}

} // namespace

extern "C" void kernel_launch(void* const* d_in, const int* in_sizes, int n_in,
                              void* d_out, int out_size, void* d_ws, size_t ws_size,
                              hipStream_t stream)
{
    const float* inp = (const float*)d_in[0];
    const float* tgt = (const float*)d_in[1];
    float* out = (float*)d_out;

    hipMemsetAsync(d_out, 0, sizeof(float), stream);   // d_out re-poisoned each call
    dim3 grid(Wd / TX, Hd / TY, 2 * (Dd / CZ));        // (10,12,8) = 960 blocks
    ncc_main<<<grid, 256, 0, stream>>>(inp, tgt, out);
}

// Round 3
// 196.704 us; speedup vs baseline: 2.4370x; 1.9589x over previous
//
#include <hip/hip_runtime.h>

namespace {

typedef _Float16 half_t;
typedef _Float16 half2_t __attribute__((ext_vector_type(2)));
typedef _Float16 half4_t __attribute__((ext_vector_type(4)));

constexpr int Wd = 160, Hd = 192, Dd = 160;
constexpr int TX = 16, TY = 16, CZ = 40;
constexpr int HW = Hd * Wd;
constexpr int LIVE = CZ + 8;               // 48 slices per block
constexpr float INV_K = 1.0f / 729.0f;
constexpr float INV_TOT = 1.0f / 9830400.0f;   // 2*160*192*160
constexpr int R4 = 17;     // xs4h row stride in half4 units (16 cols + 1 pad)
constexpr int RTH = 68;    // xsTh row stride in half units (x at 4*x)
constexpr int ROWS = 26;   // 24 halo rows + 2 pad rows absorbing lanes 240..255

// ROUND 13: 2 slices per barrier, R10 register structure restored.
// R11/R12 post-mortem: any launch_bounds tighter than (256,2) makes the
// allocator halve arch-VGPRs and spill the float4 pipeline sets to
// scratch (WRITE_SIZE 30 KB -> 300-577 MB, VALUBusy 11-13%). Occupancy
// is pinned at 2 blocks/CU by true register demand -- accept it.
// R10's residual bottleneck is sync granularity: 48 barriers/block, each
// draining lgkmcnt + arrival skew (~200-300 of ~1300 cyc/slice). This
// round: one barrier per 2 slices (24 total). Sets A and B are consumed
// + refilled in the same step; 4 LDS slice-buffers (pair k+2's writes
// separated from pair k's reads by pair k+1's barrier). Ring stays in
// LDS (proven no-spill); ring slot is a block-uniform SALU scalar.

__global__ __launch_bounds__(256, 2)
void ncc_main(const float* __restrict__ inp, const float* __restrict__ tgt,
              float* __restrict__ out)
{
    __shared__ half4_t xs4h[4][ROWS * R4];   // 4 x 3536 B
    __shared__ half_t  xsTh[4][ROWS * RTH];  // 4 x 3536 B
    __shared__ half4_t ringAB[9 * 256];      // 18432 B: z-ring {II,IT,TT,I}
    __shared__ half_t  ringT[9 * 256];       //  4608 B: z-ring {T}
    __shared__ float   red[4];

    const int tid = threadIdx.x;
    const int n  = (int)blockIdx.z >> 2;
    const int zc = (int)blockIdx.z & 3;
    const int x0 = blockIdx.x * TX, y0 = blockIdx.y * TY, z0 = zc * CZ;

    // zero the ring (thread-private slots; no sync needed)
    #pragma unroll
    for (int q = 0; q < 9; ++q) {
        ringAB[q * 256 + tid] = (half4_t)0;
        ringT[q * 256 + tid] = (half_t)0.f;
    }

    // ---- phase-1 decode: (row r 0..25) x (half h) x (field f)
    const int f = tid % 5;
    const int j = tid / 5;
    const int r = j >> 1, h = j & 1;
    const int gy = y0 - 4 + r;
    const bool yok = (tid < 240) && (gy >= 0) && (gy < Hd);
    const int gyc = min(max(gy, 0), Hd - 1);
    const int gxb = x0 - 4 + 8 * h;
    const bool uI = (f == 0) || (f == 1) || (f == 3);
    const float bI = (f == 0) ? 1.f : 0.f;
    const float bT = (f == 1 || f == 2) ? 0.5f : 0.f;
    const float bC = (f == 1 || f == 2) ? 0.5f : ((f >= 3) ? 1.f : 0.f);

#define DECODE(c) \
    int voff##c; float aI##c, aTC##c; \
    { const int gx = gxb + 4 * c; \
      const float m = (yok && gx >= 0 && gx < Wd) ? 1.f : 0.f; \
      const int gxc = min(max(gx, 0), Wd - 4); \
      voff##c = gyc * Wd + gxc; \
      aI##c = uI ? m : 0.f; aTC##c = uI ? 0.f : 0.5f * m; }
    DECODE(0) DECODE(1) DECODE(2) DECODE(3)
#undef DECODE

    const int nb = n * (Dd * HW);            // < 2^24, int math is exact
    const float* baseI = inp + nb;           // uniform -> SGPR pair
    const float* baseT = tgt + nb;

    // unified store base (both layouts are stride-4 halves): static imm offsets
    const int stoff = (f < 4) ? ((r * R4) * 4 + 32 * h + f) : (r * RTH + 32 * h);
#define MKST(b) half_t* const st_##b = (f < 4) ? ((half_t*)xs4h[b] + stoff) : (xsTh[b] + stoff);
    MKST(0) MKST(1) MKST(2) MKST(3)
#undef MKST

    // ---- phase-2 decode: one output column (yi, xi)
    const int yi = tid >> 4, xi = tid & 15;
#define MKRD(b) \
    const half4_t* const rd4_##b = &xs4h[b][yi * R4 + xi]; \
    const half_t*  const rdT_##b = &xsTh[b][yi * RTH + 4 * xi];
    MKRD(0) MKRD(1) MKRD(2) MKRD(3)
#undef MKRD

    float4 S4 = make_float4(0.f, 0.f, 0.f, 0.f);
    float ST = 0.f, acc = 0.f;
    int sl = 0;                              // block-uniform ring slot = s0 % 9

    // two prefetch sets; A = even slice of the pair, B = odd
#define DECL_SET(S) \
    float4 S##I0, S##I1, S##I2, S##I3, S##T0, S##T1, S##T2, S##T3; \
    S##I0 = S##I1 = S##I2 = S##I3 = make_float4(0.f, 0.f, 0.f, 0.f); \
    S##T0 = S##T1 = S##T2 = S##T3 = S##I0;
    DECL_SET(A) DECL_SET(B)
#undef DECL_SET

#define PRELOAD(S, zz) { \
    const float* pI = baseI + (zz) * HW; \
    const float* pT = baseT + (zz) * HW; \
    S##I0 = *(const float4*)(pI + voff0); S##T0 = *(const float4*)(pT + voff0); \
    S##I1 = *(const float4*)(pI + voff1); S##T1 = *(const float4*)(pT + voff1); \
    S##I2 = *(const float4*)(pI + voff2); S##T2 = *(const float4*)(pT + voff2); \
    S##I3 = *(const float4*)(pI + voff3); S##T3 = *(const float4*)(pT + voff3); }

    // prologue: s=0 -> set A, s=1 -> set B
    if (z0 - 4 >= 0) PRELOAD(A, z0 - 4)
    if (z0 - 3 >= 0) PRELOAD(B, z0 - 3)

#define PRODC(S, c, P0, P1, P2, P3) { \
    P0 = fmaf(S##I##c.x, aI##c, fmaf(S##T##c.x, aTC##c, aTC##c)) * fmaf(S##I##c.x, bI, fmaf(S##T##c.x, bT, bC)); \
    P1 = fmaf(S##I##c.y, aI##c, fmaf(S##T##c.y, aTC##c, aTC##c)) * fmaf(S##I##c.y, bI, fmaf(S##T##c.y, bT, bC)); \
    P2 = fmaf(S##I##c.z, aI##c, fmaf(S##T##c.z, aTC##c, aTC##c)) * fmaf(S##I##c.z, bI, fmaf(S##T##c.z, bT, bC)); \
    P3 = fmaf(S##I##c.w, aI##c, fmaf(S##T##c.w, aTC##c, aTC##c)) * fmaf(S##I##c.w, bI, fmaf(S##T##c.w, bT, bC)); }

    // pre-barrier half: x-prefix products from SET, depth-2 prefetch, LDS store
#define HALF_PRE(SET, S, ZOK, STP) { \
    float o0, o1, o2, o3, o4, o5, o6, o7; \
    if (ZOK) { \
        float p0, p1, p2, p3, p4, p5, p6, p7; \
        float p8, p9, p10, p11, p12, p13, p14, p15; \
        PRODC(SET, 0, p0,  p1,  p2,  p3) \
        PRODC(SET, 1, p4,  p5,  p6,  p7) \
        PRODC(SET, 2, p8,  p9,  p10, p11) \
        PRODC(SET, 3, p12, p13, p14, p15) \
        float ss = p0 + p1 + p2 + p3 + p4 + p5 + p6 + p7 + p8; \
        o0 = ss; \
        ss += p9  - p0; o1 = ss; \
        ss += p10 - p1; o2 = ss; \
        ss += p11 - p2; o3 = ss; \
        ss += p12 - p3; o4 = ss; \
        ss += p13 - p4; o5 = ss; \
        ss += p14 - p5; o6 = ss; \
        ss += p15 - p6; o7 = ss; \
    } \
    {   /* prefetch slice S+2 into the same set (depth-2 pipeline) */ \
        const int zi2 = z0 - 2 + (S); \
        if ((S) + 2 < LIVE && zi2 >= 0 && zi2 < Dd) PRELOAD(SET, zi2) \
    } \
    if (ZOK) { \
        STP[0]  = (half_t)o0; STP[4]  = (half_t)o1; \
        STP[8]  = (half_t)o2; STP[12] = (half_t)o3; \
        STP[16] = (half_t)o4; STP[20] = (half_t)o5; \
        STP[24] = (half_t)o6; STP[28] = (half_t)o7; \
    } }

    // post-barrier half: 9-row y-sum, LDS z-ring update, output accumulate
#define HALF_POST(RD4, RDT, ZOK, S, SLOT) { \
    half2_t a01 = (half2_t)0, a23 = (half2_t)0; \
    half_t aT = (half_t)0.f; \
    if (ZOK) { \
        _Pragma("unroll") \
        for (int k = 0; k < 9; ++k) { \
            const half4_t v = RD4[k * R4]; \
            const half2_t vlo = {v.x, v.y}; \
            const half2_t vhi = {v.z, v.w}; \
            a01 += vlo; a23 += vhi; \
            aT += RDT[k * RTH]; \
        } \
    } \
    {   /* LDS z-ring (thread-private slot; SLOT is block-uniform) */ \
        const half4_t oAB = ringAB[(SLOT) * 256 + tid]; \
        const half_t  oT  = ringT[(SLOT) * 256 + tid]; \
        S4.x += (float)a01.x - (float)oAB.x; \
        S4.y += (float)a01.y - (float)oAB.y; \
        S4.z += (float)a23.x - (float)oAB.z; \
        S4.w += (float)a23.y - (float)oAB.w; \
        ST   += (float)aT - (float)oT; \
        const half4_t nAB = {a01.x, a01.y, a23.x, a23.y}; \
        ringAB[(SLOT) * 256 + tid] = nAB; \
        ringT[(SLOT) * 256 + tid]  = aT; \
    } \
    if ((S) >= 8) {                                 /* output z = z0+S-8 */ \
        const float sii = S4.x, sit = S4.y, stt = S4.z, si = S4.w, stv = ST; \
        const float cross = sit - si * stv * INV_K; \
        const float tvar  = stt - stv * stv * INV_K; \
        const float ivar  = sii - si  * si  * INV_K; \
        acc += cross * cross * __builtin_amdgcn_rcpf(tvar * ivar + 1e-5f); \
    } }

    // one pair: slices s0 (set A, buf BA) and s0+1 (set B, buf BB), ONE barrier
#define PAIR(U, BA, BB) { \
    const int s0 = tb + 2 * (U); \
    const int s1 = s0 + 1; \
    const int zi0 = z0 - 4 + s0; \
    const bool zok0 = (zi0 >= 0) && (zi0 < Dd);     /* uniform */ \
    const bool zok1 = (zi0 + 1 >= 0) && (zi0 + 1 < Dd); \
    HALF_PRE(A, s0, zok0, st_##BA) \
    HALF_PRE(B, s1, zok1, st_##BB) \
    __syncthreads(); \
    const int sl1 = (sl == 8) ? 0 : sl + 1; \
    HALF_POST(rd4_##BA, rdT_##BA, zok0, s0, sl) \
    HALF_POST(rd4_##BB, rdT_##BB, zok1, s1, sl1) \
    sl = (sl1 == 8) ? 0 : sl1 + 1; \
}

    for (int tb = 0; tb < 48; tb += 24) {          // 2 x 12 pairs = 48 slices
        PAIR(0, 0, 1)  PAIR(1, 2, 3)  PAIR(2, 0, 1)  PAIR(3, 2, 3)
        PAIR(4, 0, 1)  PAIR(5, 2, 3)  PAIR(6, 0, 1)  PAIR(7, 2, 3)
        PAIR(8, 0, 1)  PAIR(9, 2, 3)  PAIR(10, 0, 1) PAIR(11, 2, 3)
    }
#undef PAIR
#undef HALF_POST
#undef HALF_PRE
#undef PRELOAD
#undef PRODC

    // ---- block reduction + fused finalize (one atomic per block)
    #pragma unroll
    for (int off = 32; off > 0; off >>= 1) acc += __shfl_down(acc, off, 64);
    if ((tid & 63) == 0) red[tid >> 6] = acc;
    __syncthreads();
    if (tid == 0) {
        const float tot = red[0] + red[1] + red[2] + red[3];
        atomicAdd(out, -tot * INV_TOT);
    }
}

} // namespace

extern "C" void kernel_launch(void* const* d_in, const int* in_sizes, int n_in,
                              void* d_out, int out_size, void* d_ws, size_t ws_size,
                              hipStream_t stream)
{
    const float* inp = (const float*)d_in[0];
    const float* tgt = (const float*)d_in[1];
    float* out = (float*)d_out;

    hipMemsetAsync(d_out, 0, sizeof(float), stream);   // d_out re-poisoned each call
    dim3 grid(Wd / TX, Hd / TY, 2 * (Dd / CZ));        // (10,12,8) = 960 blocks
    ncc_main<<<grid, 256, 0, stream>>>(inp, tgt, out);
}

// Round 4
// 167.753 us; speedup vs baseline: 2.8576x; 1.1726x over previous
//
#include <hip/hip_runtime.h>

namespace {

typedef _Float16 half_t;
typedef _Float16 half2_t __attribute__((ext_vector_type(2)));
typedef _Float16 half4_t __attribute__((ext_vector_type(4)));

constexpr int Wd = 160, Hd = 192, Dd = 160;
constexpr int TX = 16, TY = 16, CZ = 40;
constexpr int HW = Hd * Wd;
constexpr int LIVE = CZ + 8;               // 48 slices per block
constexpr float INV_K = 1.0f / 729.0f;
constexpr float INV_TOT = 1.0f / 9830400.0f;   // 2*160*192*160
constexpr int R4 = 17;     // xs4h row stride in half4 units (16 cols + 1 pad)
constexpr int RTH = 68;    // xsTh row stride in half units (x at 4*x)
constexpr int ROWS = 26;   // 24 halo rows + 2 pad rows absorbing lanes 240..255

// ROUND 14: R10 structure restored verbatim; ONLY change is dropping the
// waves-per-eu arg from __launch_bounds__. Post-mortem of R10-R13: measured
// residency tracked the SECOND launch-bounds argument (2 -> ~2 blocks/CU,
// 4 -> ~3.4-4), not the resource limits (R10: LDS 37.4K allows 4 blocks,
// VGPR 84 allows 6 waves/SIMD). hipcc lowers the arg to amdgpu-waves-per-eu,
// which appears to pin the residency target. With plain (256) the runtime
// should pack 4 blocks/CU (LDS-limited) -> double the independent barrier
// groups to hide the per-slice latency (R10: all pipes <= 50% busy).
// R11/R12 lesson stands: never constrain the allocator below ~150 regs --
// pipeline state spills to scratch (WRITE_SIZE 30 KB -> 300-577 MB).
// R13 lesson: merging 2 slices/barrier raises VGPR to 128 and loses 28%.

__global__ __launch_bounds__(256)
void ncc_main(const float* __restrict__ inp, const float* __restrict__ tgt,
              float* __restrict__ out)
{
    __shared__ half4_t xs4h[2][ROWS * R4];   // 2 x 3536 B
    __shared__ half_t  xsTh[2][ROWS * RTH];  // 2 x 3536 B
    __shared__ half4_t ringAB[9 * 256];      // 18432 B: z-ring {II,IT,TT,I}
    __shared__ half_t  ringT[9 * 256];       //  4608 B: z-ring {T}
    __shared__ float   red[4];

    const int tid = threadIdx.x;
    const int n  = (int)blockIdx.z >> 2;
    const int zc = (int)blockIdx.z & 3;
    const int x0 = blockIdx.x * TX, y0 = blockIdx.y * TY, z0 = zc * CZ;

    // zero the ring (thread-private slots; no sync needed)
    #pragma unroll
    for (int q = 0; q < 9; ++q) {
        ringAB[q * 256 + tid] = (half4_t)0;
        ringT[q * 256 + tid] = (half_t)0.f;
    }

    // ---- phase-1 decode: (row r 0..25) x (half h) x (field f)
    const int f = tid % 5;
    const int j = tid / 5;
    const int r = j >> 1, h = j & 1;
    const int gy = y0 - 4 + r;
    const bool yok = (tid < 240) && (gy >= 0) && (gy < Hd);
    const int gyc = min(max(gy, 0), Hd - 1);
    const int gxb = x0 - 4 + 8 * h;
    const bool uI = (f == 0) || (f == 1) || (f == 3);
    const float bI = (f == 0) ? 1.f : 0.f;
    const float bT = (f == 1 || f == 2) ? 0.5f : 0.f;
    const float bC = (f == 1 || f == 2) ? 0.5f : ((f >= 3) ? 1.f : 0.f);

#define DECODE(c) \
    int voff##c; float aI##c, aTC##c; \
    { const int gx = gxb + 4 * c; \
      const float m = (yok && gx >= 0 && gx < Wd) ? 1.f : 0.f; \
      const int gxc = min(max(gx, 0), Wd - 4); \
      voff##c = gyc * Wd + gxc; \
      aI##c = uI ? m : 0.f; aTC##c = uI ? 0.f : 0.5f * m; }
    DECODE(0) DECODE(1) DECODE(2) DECODE(3)
#undef DECODE

    const int nb = n * (Dd * HW);            // < 2^24, int math is exact
    const float* baseI = inp + nb;           // uniform -> SGPR pair
    const float* baseT = tgt + nb;

    // unified store base (both layouts are stride-4 halves): static imm offsets
    const int stoff = (f < 4) ? ((r * R4) * 4 + 32 * h + f) : (r * RTH + 32 * h);
    half_t* const st0 = (f < 4) ? ((half_t*)xs4h[0] + stoff) : (xsTh[0] + stoff);
    half_t* const st1 = (f < 4) ? ((half_t*)xs4h[1] + stoff) : (xsTh[1] + stoff);

    // ---- phase-2 decode: one output column (yi, xi)
    const int yi = tid >> 4, xi = tid & 15;
    const half4_t* const rd4_0 = &xs4h[0][yi * R4 + xi];
    const half4_t* const rd4_1 = &xs4h[1][yi * R4 + xi];
    const half_t*  const rdT_0 = &xsTh[0][yi * RTH + 4 * xi];
    const half_t*  const rdT_1 = &xsTh[1][yi * RTH + 4 * xi];

    float4 S4 = make_float4(0.f, 0.f, 0.f, 0.f);
    float ST = 0.f, acc = 0.f;

    // two prefetch sets, roles alternate with static slice parity
#define DECL_SET(S) \
    float4 S##I0, S##I1, S##I2, S##I3, S##T0, S##T1, S##T2, S##T3; \
    S##I0 = S##I1 = S##I2 = S##I3 = make_float4(0.f, 0.f, 0.f, 0.f); \
    S##T0 = S##T1 = S##T2 = S##T3 = S##I0;
    DECL_SET(A) DECL_SET(B)
#undef DECL_SET

#define PRELOAD(S, zz) { \
    const float* pI = baseI + (zz) * HW; \
    const float* pT = baseT + (zz) * HW; \
    S##I0 = *(const float4*)(pI + voff0); S##T0 = *(const float4*)(pT + voff0); \
    S##I1 = *(const float4*)(pI + voff1); S##T1 = *(const float4*)(pT + voff1); \
    S##I2 = *(const float4*)(pI + voff2); S##T2 = *(const float4*)(pT + voff2); \
    S##I3 = *(const float4*)(pI + voff3); S##T3 = *(const float4*)(pT + voff3); }

    // prologue: s=0 -> set A (even), s=1 -> set B (odd)
    if (z0 - 4 >= 0) PRELOAD(A, z0 - 4)
    if (z0 - 3 >= 0) PRELOAD(B, z0 - 3)

#define PRODC(S, c, P0, P1, P2, P3) { \
    P0 = fmaf(S##I##c.x, aI##c, fmaf(S##T##c.x, aTC##c, aTC##c)) * fmaf(S##I##c.x, bI, fmaf(S##T##c.x, bT, bC)); \
    P1 = fmaf(S##I##c.y, aI##c, fmaf(S##T##c.y, aTC##c, aTC##c)) * fmaf(S##I##c.y, bI, fmaf(S##T##c.y, bT, bC)); \
    P2 = fmaf(S##I##c.z, aI##c, fmaf(S##T##c.z, aTC##c, aTC##c)) * fmaf(S##I##c.z, bI, fmaf(S##T##c.z, bT, bC)); \
    P3 = fmaf(S##I##c.w, aI##c, fmaf(S##T##c.w, aTC##c, aTC##c)) * fmaf(S##I##c.w, bI, fmaf(S##T##c.w, bT, bC)); }

    // body for one slice; SET = prefetch set holding slice s, also the
    // target for the s+2 load (same parity)
#define SLICE_BODY(SET) { \
    const int zi = z0 - 4 + s; \
    const bool zok = (zi >= 0) && (zi < Dd);        /* uniform */ \
    const int sl = u % 9;                           /* static */ \
    const int pb = u & 1;                           /* static */ \
    float o0, o1, o2, o3, o4, o5, o6, o7; \
    if (zok) { \
        float p0, p1, p2, p3, p4, p5, p6, p7; \
        float p8, p9, p10, p11, p12, p13, p14, p15; \
        PRODC(SET, 0, p0,  p1,  p2,  p3) \
        PRODC(SET, 1, p4,  p5,  p6,  p7) \
        PRODC(SET, 2, p8,  p9,  p10, p11) \
        PRODC(SET, 3, p12, p13, p14, p15) \
        float ss = p0 + p1 + p2 + p3 + p4 + p5 + p6 + p7 + p8; \
        o0 = ss; \
        ss += p9  - p0; o1 = ss; \
        ss += p10 - p1; o2 = ss; \
        ss += p11 - p2; o3 = ss; \
        ss += p12 - p3; o4 = ss; \
        ss += p13 - p4; o5 = ss; \
        ss += p14 - p5; o6 = ss; \
        ss += p15 - p6; o7 = ss; \
    } \
    {   /* prefetch slice s+2 into the same set (depth-2 pipeline) */ \
        const int zi2 = z0 - 2 + s; \
        if ((s + 2) < LIVE && zi2 >= 0 && zi2 < Dd) PRELOAD(SET, zi2) \
    } \
    if (zok) { \
        half_t* const st = pb ? st1 : st0; \
        st[0]  = (half_t)o0; st[4]  = (half_t)o1; \
        st[8]  = (half_t)o2; st[12] = (half_t)o3; \
        st[16] = (half_t)o4; st[20] = (half_t)o5; \
        st[24] = (half_t)o6; st[28] = (half_t)o7; \
    } \
    __syncthreads();                                /* single barrier */ \
    half2_t a01 = (half2_t)0, a23 = (half2_t)0; \
    half_t aT = (half_t)0.f; \
    if (zok) { \
        const half4_t* const rd4 = pb ? rd4_1 : rd4_0; \
        const half_t*  const rdT = pb ? rdT_1 : rdT_0; \
        _Pragma("unroll") \
        for (int k = 0; k < 9; ++k) { \
            const half4_t v = rd4[k * R4]; \
            const half2_t vlo = {v.x, v.y}; \
            const half2_t vhi = {v.z, v.w}; \
            a01 += vlo; a23 += vhi; \
            aT += rdT[k * RTH]; \
        } \
    } \
    {   /* LDS z-ring (thread-private, static slot offsets, no sync) */ \
        const half4_t oAB = ringAB[sl * 256 + tid]; \
        const half_t  oT  = ringT[sl * 256 + tid]; \
        S4.x += (float)a01.x - (float)oAB.x; \
        S4.y += (float)a01.y - (float)oAB.y; \
        S4.z += (float)a23.x - (float)oAB.z; \
        S4.w += (float)a23.y - (float)oAB.w; \
        ST   += (float)aT - (float)oT; \
        const half4_t nAB = {a01.x, a01.y, a23.x, a23.y}; \
        ringAB[sl * 256 + tid] = nAB; \
        ringT[sl * 256 + tid]  = aT; \
    } \
    if (s >= 8) {                                   /* output z = z0+s-8 */ \
        const float sii = S4.x, sit = S4.y, stt = S4.z, si = S4.w, stv = ST; \
        const float cross = sit - si * stv * INV_K; \
        const float tvar  = stt - stv * stv * INV_K; \
        const float ivar  = sii - si  * si  * INV_K; \
        acc += cross * cross * __builtin_amdgcn_rcpf(tvar * ivar + 1e-5f); \
    } }

    for (int tb = 0; tb < 54; tb += 18) {          // 48 live; 18-unroll
        #pragma unroll
        for (int u = 0; u < 18; ++u) {
            const int s = tb + u;                  // block-uniform
            if (s < LIVE) {
                if ((u & 1) == 0) SLICE_BODY(A)
                else              SLICE_BODY(B)
            }
        }
    }
#undef SLICE_BODY
#undef PRELOAD
#undef PRODC

    // ---- block reduction + fused finalize (one atomic per block)
    #pragma unroll
    for (int off = 32; off > 0; off >>= 1) acc += __shfl_down(acc, off, 64);
    if ((tid & 63) == 0) red[tid >> 6] = acc;
    __syncthreads();
    if (tid == 0) {
        const float tot = red[0] + red[1] + red[2] + red[3];
        atomicAdd(out, -tot * INV_TOT);
    }
}

} // namespace

extern "C" void kernel_launch(void* const* d_in, const int* in_sizes, int n_in,
                              void* d_out, int out_size, void* d_ws, size_t ws_size,
                              hipStream_t stream)
{
    const float* inp = (const float*)d_in[0];
    const float* tgt = (const float*)d_in[1];
    float* out = (float*)d_out;

    hipMemsetAsync(d_out, 0, sizeof(float), stream);   // d_out re-poisoned each call
    dim3 grid(Wd / TX, Hd / TY, 2 * (Dd / CZ));        // (10,12,8) = 960 blocks
    ncc_main<<<grid, 256, 0, stream>>>(inp, tgt, out);
}